// Round 8
// baseline (242.599 us; speedup 1.0000x reference)
//
#include <hip/hip_runtime.h>

// Rx(theta) on qubit 0 (MSB of state index) of a 24-qubit state.
// Inputs: state_re [2^24] f32, state_im [2^24] f32, theta [1] f32.
// Output: [2, 2^24] f32 = stack(out_re, out_im).
//
//   s = sin(theta/2), c = cos(theta/2)
//   out0 = (c*a_re + s*b_im) + i(c*a_im - s*b_re)
//   out1 = (c*b_re + s*a_im) + i(c*b_im - s*a_re)
//
// R2: 83us (8 streams/wave, loop, no pipeline). FETCH=64MB exactly half.
// R5: ~75us (2-family split: 2 loads+2 stores per wave, one-shot).
// R6: NT stores = neutral (FETCH unchanged) -> allocation theory dead.
// R7: infra failure (container died twice) -- experiment never ran; resubmit.
// R7 theory: no counter saturated (VALU 9%, occ 69%, EA 2.5 vs fill's 6.7
//   TB/s) -> wave-lifetime/issue regime. The 6.3TB/s copy and 6.7TB/s fill
//   both LOOP; our one-shot waves serialize {load-wait-store-drain} per
//   generation. Fix: per-thread loop (8 iters) + software pipeline
//   (prefetch next loads before current stores). Family math is branchless:
//   sg = fam ? -s : s;  r0 = c*x0 + sg*x1 -> out0;  r1 = c*x1 - sg*x0 -> out1.

typedef float f32x4 __attribute__((ext_vector_type(4)));

constexpr int NV      = 1 << 21;          // float4 elements per half
constexpr int BLOCKS  = 2048;             // 8 blocks/CU x 256 CUs
constexpr int FBLK    = BLOCKS / 2;       // blocks per family
constexpr int STRIDE  = FBLK * 256;       // threads per family = 2^18
constexpr int ITERS   = NV / STRIDE;      // 8 iterations per thread

__global__ __launch_bounds__(256) void rx_gate_kernel(
    const f32x4* __restrict__ sre,
    const f32x4* __restrict__ sim,
    const float* __restrict__ theta,
    f32x4* __restrict__ out)
{
    const float t2 = theta[0] * 0.5f;
    const float s = sinf(t2);
    const float c = cosf(t2);

    const int fam = blockIdx.x & 1;
    const int tid = (blockIdx.x >> 1) * blockDim.x + threadIdx.x;  // [0, 2^18)

    // Family A (fam=0): x0=a_re, x1=b_im -> o0_re=c*x0+s*x1 @out[0:NV),
    //                                       o1_im=c*x1-s*x0 @out[3NV:4NV)
    // Family B (fam=1): x0=a_im, x1=b_re -> o0_im=c*x0-s*x1 @out[2NV:3NV),
    //                                       o1_re=c*x1+s*x0 @out[NV:2NV)
    // Both collapse to r0 = c*x0 + sg*x1, r1 = c*x1 - sg*x0 with sg=+/-s.
    const float sg = fam ? -s : s;
    const f32x4* __restrict__ in0 = fam ? sim : sre;
    const f32x4* __restrict__ in1 = (fam ? sre : sim) + NV;
    f32x4* __restrict__ o0 = out + (fam ? 2 * NV : 0);
    f32x4* __restrict__ o1 = out + (fam ? NV : 3 * NV);

    // Software-pipelined loop: loads for k+1 issue before stores for k.
    int i = tid;
    f32x4 x0 = in0[i];
    f32x4 x1 = in1[i];
#pragma unroll
    for (int k = 0; k < ITERS - 1; ++k) {
        const int inext = i + STRIDE;
        const f32x4 n0 = in0[inext];
        const f32x4 n1 = in1[inext];
        o0[i] = c * x0 + sg * x1;
        o1[i] = c * x1 - sg * x0;
        x0 = n0;
        x1 = n1;
        i = inext;
    }
    o0[i] = c * x0 + sg * x1;
    o1[i] = c * x1 - sg * x0;
}

extern "C" void kernel_launch(void* const* d_in, const int* in_sizes, int n_in,
                              void* d_out, int out_size, void* d_ws, size_t ws_size,
                              hipStream_t stream) {
    const f32x4* sre   = (const f32x4*)d_in[0];
    const f32x4* sim   = (const f32x4*)d_in[1];
    const float* theta = (const float*)d_in[2];
    f32x4* out = (f32x4*)d_out;

    rx_gate_kernel<<<BLOCKS, 256, 0, stream>>>(sre, sim, theta, out);
}